// Round 6
// baseline (278.264 us; speedup 1.0000x reference)
//
#include <hip/hip_runtime.h>
#include <stdint.h>

#define B_  2
#define S_  2048
#define D_  1024
#define H_  16
#define DK_ 64
#define VST 2176   // q2T padded row stride (4352 B = 17*256): breaks 4KB aliasing

typedef unsigned short u16;
typedef short bf16x8 __attribute__((ext_vector_type(8)));
typedef float f32x4  __attribute__((ext_vector_type(4)));

#define MFMA(a,b,c) __builtin_amdgcn_mfma_f32_16x16x32_bf16((a),(b),(c),0,0,0)
#define EXP2(x) __builtin_amdgcn_exp2f(x)

static __device__ __forceinline__ u16 f2bf(float f) {
    uint32_t u = __float_as_uint(f);
    u += 0x7fffu + ((u >> 16) & 1u);   // RNE
    return (u16)(u >> 16);
}
// pack two f32 -> two bf16 (round-half-up ~= RNE for continuous data): 2 adds + 1 perm
static __device__ __forceinline__ uint32_t pk2(float x, float y) {
    return __builtin_amdgcn_perm(__float_as_uint(y) + 0x8000u,
                                 __float_as_uint(x) + 0x8000u, 0x07060302u);
}
static __device__ __forceinline__ bf16x8 cvt8(float4 a, float4 b) {
    union { uint32_t u[4]; bf16x8 v; } r;
    r.u[0] = pk2(a.x, a.y); r.u[1] = pk2(a.z, a.w);
    r.u[2] = pk2(b.x, b.y); r.u[3] = pk2(b.z, b.w);
    return r.v;
}

typedef const __attribute__((address_space(1))) void* gas_p;
typedef __attribute__((address_space(3))) void* las_p;
static __device__ __forceinline__ void gld16(const void* g, void* l) {
    __builtin_amdgcn_global_load_lds((gas_p)g, (las_p)l, 16, 0, 0);
}

// ---------------- projection GEMMs: C = X @ W^T + bias (f32 in, bf16 out) ----
// Reads X,W directly in f32 (no conv pre-pass): staged 16B-chunk-XOR-swizzled
// f32 tiles in LDS, converted to bf16 at fragment load.
// z=0: v -> v2 (B,H,S,DK), scaled by 0.125*log2(e).  z=1: k -> k2.
// z=2: q -> q2T (B,H,DK,S) padded stride VST.
// Epilogues go through a per-wave LDS transpose so global stores are 16B runs.
// Block remap: M-block = flatid&31 -> all N-blocks of an M-row group share XCD.

__global__ __launch_bounds__(256) void proj_gemm(
    const float* __restrict__ Xv, const float* __restrict__ Xk, const float* __restrict__ Xq,
    const float* __restrict__ Wv, const float* __restrict__ Wk, const float* __restrict__ Wq,
    const float* __restrict__ bv, const float* __restrict__ bk, const float* __restrict__ bq,
    u16* __restrict__ v2, u16* __restrict__ k2, u16* __restrict__ q2T)
{
    __shared__ alignas(16) char smem[40960];   // union: lA(16K)+lB(16K) / epi(40K)
    float* lA = (float*)smem;
    float* lB = (float*)(smem + 16384);
    u16*   epi = (u16*)smem;                   // [wave][64][80] u16

    const int z = blockIdx.z;
    const float* A = (z == 0) ? Xv : (z == 1 ? Xk : Xq);
    const float* W = (z == 0) ? Wv : (z == 1 ? Wk : Wq);
    const float* bias = (z == 0) ? bv : (z == 1 ? bk : bq);

    const int tid = threadIdx.x;
    const int lane = tid & 63, wave = tid >> 6;
    const int wm = wave >> 1, wn = wave & 1;
    const int q = lane >> 4, l15 = lane & 15;
    const int q4 = q * 4;

    // XCD grouping: dispatch-flat f = y*8+x; M-block = f&31 keys the XCD
    const int f = blockIdx.y * 8 + blockIdx.x;
    const int rowbase = (f & 31) * 128;
    const int colbase = (f >> 5) * 128;

    // staging: 8 rows x 8 chunks(16B) per gld16; chunk XOR-swizzled by row&7
    const int srow8 = lane >> 3;
    const int cs = lane & 7;
    const int cg = cs ^ srow8;
    const float* gA = A + (size_t)(rowbase + wave * 32 + srow8) * D_ + cg * 4;
    const float* gW = W + (size_t)(colbase + wave * 32 + srow8) * D_ + cg * 4;
    float* lAp = lA + (wave * 32 + srow8) * 32 + cs * 4;
    float* lBp = lB + (wave * 32 + srow8) * 32 + cs * 4;

    // fragment chunk offsets (f32 chunks 2q, 2q+1 of a 32-f32 row, XOR by l15&7)
    const int sw = l15 & 7;
    const int ca = ((2 * q) ^ sw) * 4;
    const int cb = ((2 * q + 1) ^ sw) * 4;

    f32x4 acc[4][4] = {};

    for (int k0 = 0; k0 < D_; k0 += 32) {
        #pragma unroll
        for (int j = 0; j < 4; j++)
            gld16(gA + k0 + j * 8 * D_, lAp + j * 8 * 32);
        #pragma unroll
        for (int j = 0; j < 4; j++)
            gld16(gW + k0 + j * 8 * D_, lBp + j * 8 * 32);
        __syncthreads();
        bf16x8 af[4], bfr[4];
        #pragma unroll
        for (int mi = 0; mi < 4; mi++) {
            const int r = (wm * 64 + mi * 16 + l15) * 32;
            af[mi] = cvt8(*(const float4*)&lA[r + ca], *(const float4*)&lA[r + cb]);
        }
        #pragma unroll
        for (int ni = 0; ni < 4; ni++) {
            const int r = (wn * 64 + ni * 16 + l15) * 32;
            bfr[ni] = cvt8(*(const float4*)&lB[r + ca], *(const float4*)&lB[r + cb]);
        }
        #pragma unroll
        for (int mi = 0; mi < 4; mi++)
            #pragma unroll
            for (int ni = 0; ni < 4; ni++)
                acc[mi][ni] = MFMA(af[mi], bfr[ni], acc[mi][ni]);
        __syncthreads();
    }

    // ---- epilogue via per-wave LDS transpose (epi row stride 80 u16 = 160 B) ----
    u16* ep = epi + wave * (64 * 80);
    const int h = (colbase + wn * 64) >> 6;     // wave's single head
    const int Mrow0 = rowbase + wm * 64;        // 64-aligned, no batch straddle
    const int bb = Mrow0 >> 11;

    if (z < 2) {
        u16* outp = (z == 0) ? v2 : k2;
        const float scale = (z == 0) ? 0.18033688011112042f : 1.0f;  // 0.125*log2(e)
        #pragma unroll
        for (int mi = 0; mi < 4; mi++)
            #pragma unroll
            for (int ni = 0; ni < 4; ni++) {
                const float bc = bias[colbase + wn * 64 + ni * 16 + l15];
                #pragma unroll
                for (int rg = 0; rg < 4; rg++)
                    ep[(mi * 16 + q4 + rg) * 80 + ni * 16 + l15] =
                        f2bf((acc[mi][ni][rg] + bc) * scale);
            }
        asm volatile("s_waitcnt lgkmcnt(0)" ::: "memory");
        // lane = s-row 0..63; store 64 dk contiguous (8 x 16B)
        const int s = (Mrow0 + lane) & (S_ - 1);
        u16* gb = outp + ((size_t)(bb * H_ + h) * S_ + s) * DK_;
        #pragma unroll
        for (int j = 0; j < 8; j++)
            *(uint4*)(gb + j * 8) = *(const uint4*)&ep[lane * 80 + j * 8];
    } else {
        #pragma unroll
        for (int mi = 0; mi < 4; mi++)
            #pragma unroll
            for (int ni = 0; ni < 4; ni++) {
                const float bc = bias[colbase + wn * 64 + ni * 16 + l15];
                uint2 pk;
                pk.x = pk2(acc[mi][ni][0] + bc, acc[mi][ni][1] + bc);
                pk.y = pk2(acc[mi][ni][2] + bc, acc[mi][ni][3] + bc);
                *(uint2*)&ep[(ni * 16 + l15) * 80 + mi * 16 + q4] = pk;
            }
        asm volatile("s_waitcnt lgkmcnt(0)" ::: "memory");
        // lane = dk-local 0..63 (head h owns cols [h*64, h*64+64), so global
        // dk row base is (bb*H+h)*DK + lane — R5's bug had a spurious -wn*64).
        const int s0g = Mrow0 & (S_ - 1);
        u16* gb = q2T + ((size_t)(bb * H_ + h) * DK_ + lane) * VST + s0g;
        #pragma unroll
        for (int j = 0; j < 8; j++)
            *(uint4*)(gb + j * 8) = *(const uint4*)&ep[lane * 80 + j * 8];
    }
}

// ---------------- flash attention (XCD-grouped grid) ----------------
// Roles (source bug): "query"=v2 (prescaled, log2 domain), "key"=k2, "value"=q2.
// bh = id&31 -> the 16 s-blocks of one (b,h) share an XCD's L2.

__global__ __launch_bounds__(256) void flash_attn(
    const u16* __restrict__ v2, const u16* __restrict__ k2,
    const u16* __restrict__ q2T, u16* __restrict__ Ob)
{
    __shared__ alignas(16) u16 lK[2][64 * 64];
    __shared__ alignas(16) u16 lV[2][64 * 64];
    __shared__ alignas(16) u16 ldsP[4][2][16][68];  // [wave][group][s][t+pad]

    const int tid = threadIdx.x;
    const int lane = tid & 63, wave = tid >> 6;
    const int q = lane >> 4, l15 = lane & 15;
    const int q4 = q * 4;
    const int bh = blockIdx.x & 31;
    const int sbase = (blockIdx.x >> 5) * 128;

    const u16* Qp = v2  + (size_t)bh * S_ * DK_;
    const u16* Kp = k2  + (size_t)bh * S_ * DK_;
    const u16* Vp = q2T + (size_t)bh * DK_ * VST;

    const int srow8 = lane >> 3;
    const int cs    = lane & 7;
    const int cg    = cs ^ srow8;
    const int krow0 = wave * 16 + srow8;

    bf16x8 bq[2][2];
    #pragma unroll
    for (int g = 0; g < 2; g++) {
        const u16* qp = Qp + (size_t)(sbase + g * 64 + wave * 16 + l15) * DK_ + q * 8;
        bq[g][0] = *(const bf16x8*)(qp);
        bq[g][1] = *(const bf16x8*)(qp + 32);
    }

    bf16x8 ones;
    #pragma unroll
    for (int i = 0; i < 8; i++) ones[i] = (short)0x3F80;

    f32x4 o_acc[2][4] = {};
    f32x4 o_l[2] = {};

    const int sw = l15 & 7;
    const int fc0 = (q ^ sw) * 8;
    const int fc1 = fc0 ^ 32;

    {
        const u16* kg = Kp + (size_t)krow0 * DK_ + cg * 8;
        const u16* vg = Vp + (size_t)krow0 * VST + cg * 8;
        u16* lkd = &lK[0][(wave * 128) * 8 + lane * 8];
        u16* lvd = &lV[0][(wave * 128) * 8 + lane * 8];
        gld16(kg, lkd);
        gld16(kg + 8 * DK_, lkd + 64 * 8);
        gld16(vg, lvd);
        gld16(vg + (size_t)8 * VST, lvd + 64 * 8);
    }

    for (int it = 0; it < S_ / 64; ++it) {
        const int buf = it & 1;
        __syncthreads();
        if (it + 1 < S_ / 64) {
            const int nb = (it + 1) & 1;
            const int t1 = (it + 1) * 64;
            const u16* kg = Kp + (size_t)(t1 + krow0) * DK_ + cg * 8;
            const u16* vg = Vp + (size_t)krow0 * VST + t1 + cg * 8;
            u16* lkd = &lK[nb][(wave * 128) * 8 + lane * 8];
            u16* lvd = &lV[nb][(wave * 128) * 8 + lane * 8];
            gld16(kg, lkd);
            gld16(kg + 8 * DK_, lkd + 64 * 8);
            gld16(vg, lvd);
            gld16(vg + (size_t)8 * VST, lvd + 64 * 8);
        }

        f32x4 s_acc[2][4];
        #pragma unroll
        for (int mi = 0; mi < 4; mi++) {
            const int trow = mi * 16 + l15;
            bf16x8 a0 = *(const bf16x8*)&lK[buf][trow * 64 + fc0];
            bf16x8 a1 = *(const bf16x8*)&lK[buf][trow * 64 + fc1];
            #pragma unroll
            for (int g = 0; g < 2; g++) {
                f32x4 zz = {};
                zz = MFMA(a0, bq[g][0], zz);
                s_acc[g][mi] = MFMA(a1, bq[g][1], zz);
            }
        }

        #pragma unroll
        for (int g = 0; g < 2; g++)
            #pragma unroll
            for (int mi = 0; mi < 4; mi++) {
                float p0 = EXP2(s_acc[g][mi][0]);
                float p1 = EXP2(s_acc[g][mi][1]);
                float p2 = EXP2(s_acc[g][mi][2]);
                float p3 = EXP2(s_acc[g][mi][3]);
                uint2 pk;
                pk.x = __builtin_amdgcn_perm(__float_as_uint(p1), __float_as_uint(p0), 0x07060302u);
                pk.y = __builtin_amdgcn_perm(__float_as_uint(p3), __float_as_uint(p2), 0x07060302u);
                *(uint2*)&ldsP[wave][g][l15][mi * 16 + q4] = pk;
            }

        asm volatile("s_waitcnt lgkmcnt(0)" ::: "memory");

        bf16x8 bp[2][2];
        #pragma unroll
        for (int g = 0; g < 2; g++) {
            uint2* r0 = (uint2*)&bp[g][0];
            r0[0] = *(const uint2*)&ldsP[wave][g][l15][q * 8];
            r0[1] = *(const uint2*)&ldsP[wave][g][l15][q * 8 + 4];
            uint2* r1 = (uint2*)&bp[g][1];
            r1[0] = *(const uint2*)&ldsP[wave][g][l15][32 + q * 8];
            r1[1] = *(const uint2*)&ldsP[wave][g][l15][32 + q * 8 + 4];
        }

        #pragma unroll
        for (int mi = 0; mi < 4; mi++) {
            const int dkrow = mi * 16 + l15;
            bf16x8 av0 = *(const bf16x8*)&lV[buf][dkrow * 64 + fc0];
            bf16x8 av1 = *(const bf16x8*)&lV[buf][dkrow * 64 + fc1];
            #pragma unroll
            for (int g = 0; g < 2; g++) {
                o_acc[g][mi] = MFMA(av0, bp[g][0], o_acc[g][mi]);
                o_acc[g][mi] = MFMA(av1, bp[g][1], o_acc[g][mi]);
            }
        }
        #pragma unroll
        for (int g = 0; g < 2; g++) {
            o_l[g] = MFMA(ones, bp[g][0], o_l[g]);
            o_l[g] = MFMA(ones, bp[g][1], o_l[g]);
        }

        asm volatile("s_barrier" ::: "memory");
    }

    const int bb = bh >> 4, h = bh & 15;
    #pragma unroll
    for (int g = 0; g < 2; g++) {
        const float inv_l = 1.0f / o_l[g][0];
        const int s = sbase + g * 64 + wave * 16 + l15;
        #pragma unroll
        for (int mi = 0; mi < 4; mi++) {
            ushort4 o4;
            o4.x = f2bf(o_acc[g][mi][0] * inv_l);
            o4.y = f2bf(o_acc[g][mi][1] * inv_l);
            o4.z = f2bf(o_acc[g][mi][2] * inv_l);
            o4.w = f2bf(o_acc[g][mi][3] * inv_l);
            *(ushort4*)(Ob + (size_t)(bb * S_ + s) * (H_ * DK_) + h * DK_ + mi * 16 + q4) = o4;
        }
    }
}

// ---------------- output GEMM: out = O @ Wo^T + bo (Ob bf16, Wo f32-direct) --

__global__ __launch_bounds__(256) void out_gemm(
    const u16* __restrict__ Ob, const float* __restrict__ Wo,
    const float* __restrict__ bo, float* __restrict__ out)
{
    __shared__ alignas(16) u16 lA[128 * 32];    // bf16 A tile
    __shared__ alignas(16) float lB[64 * 32];   // f32 B tile (XOR-swizzled)

    const int tid = threadIdx.x;
    const int lane = tid & 63, wave = tid >> 6;
    const int wm = wave >> 1, wn = wave & 1;   // 2x2 waves: 64M x 32N each
    const int q = lane >> 4, l15 = lane & 15;
    const int q4 = q * 4;

    // XCD grouping: f = y*16+x; M-block = f&31
    const int f = blockIdx.y * 16 + blockIdx.x;
    const int rowbase = (f & 31) * 128;
    const int colbase = (f >> 5) * 64;

    // A staging (bf16): 16 rows x 4 chunks per gld16
    const int arow = wave * 32 + (lane >> 2);
    const int ascol = (lane & 3) * 8;
    const u16* gA = Ob + (size_t)(rowbase + arow) * D_ + ascol;
    u16* lAp = &lA[arow * 32 + ascol];

    // B staging (f32): 8 rows x 8 chunks per gld16, XOR-swizzled
    const int srow8 = lane >> 3;
    const int cs = lane & 7;
    const int cg = cs ^ srow8;
    const float* gW = Wo + (size_t)(colbase + wave * 16 + srow8) * D_ + cg * 4;
    float* lBp = lB + (wave * 16 + srow8) * 32 + cs * 4;

    const int aoff = (wm * 64 + l15) * 32 + q * 8;
    const int sw = l15 & 7;
    const int ca = ((2 * q) ^ sw) * 4;
    const int cb = ((2 * q + 1) ^ sw) * 4;

    f32x4 acc[4][2] = {};

    for (int k0 = 0; k0 < D_; k0 += 32) {
        gld16(gA + k0, lAp);
        gld16(gA + k0 + 16 * D_, lAp + 16 * 32);
        gld16(gW + k0, lBp);
        gld16(gW + k0 + 8 * D_, lBp + 8 * 32);
        __syncthreads();
        bf16x8 af[4], bfr[2];
        #pragma unroll
        for (int mi = 0; mi < 4; mi++)
            af[mi] = *(const bf16x8*)&lA[aoff + mi * 512];
        #pragma unroll
        for (int ni = 0; ni < 2; ni++) {
            const int r = (wn * 32 + ni * 16 + l15) * 32;
            bfr[ni] = cvt8(*(const float4*)&lB[r + ca], *(const float4*)&lB[r + cb]);
        }
        #pragma unroll
        for (int mi = 0; mi < 4; mi++)
            #pragma unroll
            for (int ni = 0; ni < 2; ni++)
                acc[mi][ni] = MFMA(af[mi], bfr[ni], acc[mi][ni]);
        __syncthreads();
    }

    #pragma unroll
    for (int mi = 0; mi < 4; mi++)
        #pragma unroll
        for (int ni = 0; ni < 2; ni++) {
            const int c = colbase + wn * 32 + ni * 16 + l15;
            const float bc = bo[c];
            #pragma unroll
            for (int rg = 0; rg < 4; rg++) {
                const int r = rowbase + wm * 64 + mi * 16 + q4 + rg;
                out[(size_t)r * D_ + c] = acc[mi][ni][rg] + bc;
            }
        }
}

// ---------------- launch ----------------

extern "C" void kernel_launch(void* const* d_in, const int* in_sizes, int n_in,
                              void* d_out, int out_size, void* d_ws, size_t ws_size,
                              hipStream_t stream) {
    const float* v  = (const float*)d_in[0];
    const float* k  = (const float*)d_in[1];
    const float* qq = (const float*)d_in[2];
    const float* Wq = (const float*)d_in[3];
    const float* bq = (const float*)d_in[4];
    const float* Wk = (const float*)d_in[5];
    const float* bk = (const float*)d_in[6];
    const float* Wv = (const float*)d_in[7];
    const float* bv = (const float*)d_in[8];
    const float* Wo = (const float*)d_in[9];
    const float* bo = (const float*)d_in[10];
    float* out = (float*)d_out;

    char* w = (char*)d_ws;
    u16* v2  = (u16*)(w + 0);           // 8 MiB (B,H,S,DK), prescaled 0.125*log2e
    u16* k2  = (u16*)(w + 8388608);     // 8 MiB (B,H,S,DK)
    u16* q2T = (u16*)(w + 16777216);    // (B,H,DK,VST) bf16 padded: 8,912,896 B
    u16* Ob  = (u16*)(w + 25690112);    // 8 MiB (B,S,H*DK) bf16

    proj_gemm<<<dim3(8, 32, 3), 256, 0, stream>>>(v, k, qq, Wv, Wk, Wq,
                                                  bv, bk, bq, v2, k2, q2T);
    flash_attn<<<dim3(512), 256, 0, stream>>>(v2, k2, q2T, Ob);
    out_gemm<<<dim3(16, 32), 256, 0, stream>>>(Ob, Wo, bo, out);
}

// Round 7
// 226.450 us; speedup vs baseline: 1.2288x; 1.2288x over previous
//
#include <hip/hip_runtime.h>
#include <stdint.h>

#define B_  2
#define S_  2048
#define D_  1024
#define H_  16
#define DK_ 64
#define VST 2176   // q2T padded row stride (4352 B = 17*256): breaks 4KB aliasing

typedef unsigned short u16;
typedef short bf16x8 __attribute__((ext_vector_type(8)));
typedef float f32x4  __attribute__((ext_vector_type(4)));

#define MFMA(a,b,c) __builtin_amdgcn_mfma_f32_16x16x32_bf16((a),(b),(c),0,0,0)
#define EXP2(x) __builtin_amdgcn_exp2f(x)

static __device__ __forceinline__ u16 f2bf(float f) {
    uint32_t u = __float_as_uint(f);
    u += 0x7fffu + ((u >> 16) & 1u);   // RNE
    return (u16)(u >> 16);
}
static __device__ __forceinline__ uint32_t pk2(float x, float y) {
    return __builtin_amdgcn_perm(__float_as_uint(y) + 0x8000u,
                                 __float_as_uint(x) + 0x8000u, 0x07060302u);
}

typedef const __attribute__((address_space(1))) void* gas_p;
typedef __attribute__((address_space(3))) void* las_p;
static __device__ __forceinline__ void gld16(const void* g, void* l) {
    __builtin_amdgcn_global_load_lds((gas_p)g, (las_p)l, 16, 0, 0);
}

// ---------------- one fused f32 -> bf16 conversion pass ----------------
// bf16 arena layout (u16 element offsets):
//   vb 0 | kb 4194304 | qb 8388608 | Wvb 12582912 | Wkb 13631488
//   Wqb 14680064 | Wob 15728640     (total 16M u16 = 32 MB)

__global__ void conv_all(const float* __restrict__ v, const float* __restrict__ k,
                         const float* __restrict__ q,
                         const float* __restrict__ Wv, const float* __restrict__ Wk,
                         const float* __restrict__ Wq, const float* __restrict__ Wo,
                         u16* __restrict__ dst) {
    const int b = blockIdx.x;
    const float* s;
    size_t loc, segbase;
    if (b < 12288) {                          // 3 X tensors, 4096 blocks each
        const int t = b >> 12;
        s = (t == 0) ? v : (t == 1 ? k : q);
        segbase = (size_t)t * 4194304;
        loc = (size_t)(b & 4095) * 1024;
    } else {                                  // 4 W tensors, 1024 blocks each
        const int t = (b - 12288) >> 10;
        s = (t == 0) ? Wv : (t == 1 ? Wk : (t == 2 ? Wq : Wo));
        segbase = 12582912 + (size_t)t * 1048576;
        loc = (size_t)(b & 1023) * 1024;
    }
    loc += threadIdx.x * 4;
    float4 f = *(const float4*)(s + loc);
    ushort4 o;
    o.x = f2bf(f.x); o.y = f2bf(f.y); o.z = f2bf(f.z); o.w = f2bf(f.w);
    *(ushort4*)(dst + segbase + loc) = o;
}

// ---------------- projection GEMMs: C = X @ W^T + bias (bf16, BK=64) ----------
// Flash-proven LDS geometry (0 bank conflicts measured): 8-row staging groups
// with chunk XOR swizzle, single-b128 fragment reads at (q^sw)*8 / ^32.
// z=0: v -> v2 (B,H,S,DK), scaled 0.125*log2(e).  z=1: k -> k2.
// z=2: q -> q2T (B,H,DK,S) padded stride VST.
// Coalesced epilogues via per-wave LDS transpose; XCD-grouped block remap.

__global__ __launch_bounds__(256) void proj_gemm(
    const u16* __restrict__ Xb, const u16* __restrict__ Wb,
    const float* __restrict__ bv, const float* __restrict__ bk, const float* __restrict__ bq,
    u16* __restrict__ v2, u16* __restrict__ k2, u16* __restrict__ q2T)
{
    __shared__ alignas(16) char smem[40960];   // union: lA(16K)+lB(16K) / epi(40K)
    u16* lA = (u16*)smem;                      // 128 x 64 bf16
    u16* lB = (u16*)(smem + 16384);
    u16* epi = (u16*)smem;                     // [wave][64][80] u16

    const int z = blockIdx.z;
    const u16* A = Xb + (size_t)z * 4194304;   // v / k / q (bf16)
    const u16* W = Wb + (size_t)z * 1048576;   // Wv / Wk / Wq (bf16)
    const float* bias = (z == 0) ? bv : (z == 1 ? bk : bq);

    const int tid = threadIdx.x;
    const int lane = tid & 63, wave = tid >> 6;
    const int wm = wave >> 1, wn = wave & 1;
    const int q = lane >> 4, l15 = lane & 15;
    const int q4 = q * 4;

    // XCD grouping: f = y*8+x; M-block = f&31 keys the XCD
    const int f = blockIdx.y * 8 + blockIdx.x;
    const int rowbase = (f & 31) * 128;
    const int colbase = (f >> 5) * 128;

    // staging: 32 rows per j-group; row = j*32 + wave*8 + (lane>>3); chunk = (lane&7)^(row&7)
    const int srow = wave * 8 + (lane >> 3);
    const int cg = (lane & 7) ^ (lane >> 3);
    const u16* gA = A + (size_t)(rowbase + srow) * D_ + cg * 8;
    const u16* gW = W + (size_t)(colbase + srow) * D_ + cg * 8;
    u16* lAp = lA + wave * 512 + lane * 8;     // lane-contiguous 16B dest
    u16* lBp = lB + wave * 512 + lane * 8;

    const int sw = l15 & 7;
    const int fo0 = (q ^ sw) * 8;              // k-chunk q
    const int fo1 = fo0 ^ 32;                  // k-chunk q+4

    f32x4 acc[4][4] = {};

    for (int k0 = 0; k0 < D_; k0 += 64) {
        #pragma unroll
        for (int j = 0; j < 4; j++) {
            gld16(gA + k0 + (size_t)j * 32 * D_, lAp + j * 2048);
            gld16(gW + k0 + (size_t)j * 32 * D_, lBp + j * 2048);
        }
        __syncthreads();
        bf16x8 a0[4], a1[4], b0[4], b1[4];
        #pragma unroll
        for (int mi = 0; mi < 4; mi++) {
            const int r = (wm * 64 + mi * 16 + l15) * 64;
            a0[mi] = *(const bf16x8*)&lA[r + fo0];
            a1[mi] = *(const bf16x8*)&lA[r + fo1];
        }
        #pragma unroll
        for (int ni = 0; ni < 4; ni++) {
            const int r = (wn * 64 + ni * 16 + l15) * 64;
            b0[ni] = *(const bf16x8*)&lB[r + fo0];
            b1[ni] = *(const bf16x8*)&lB[r + fo1];
        }
        #pragma unroll
        for (int mi = 0; mi < 4; mi++)
            #pragma unroll
            for (int ni = 0; ni < 4; ni++) {
                acc[mi][ni] = MFMA(a0[mi], b0[ni], acc[mi][ni]);
                acc[mi][ni] = MFMA(a1[mi], b1[ni], acc[mi][ni]);
            }
        __syncthreads();
    }

    // ---- epilogue via per-wave LDS transpose (stride 80 u16) ----
    u16* ep = epi + wave * (64 * 80);
    const int h = (colbase + wn * 64) >> 6;     // wave's single head
    const int Mrow0 = rowbase + wm * 64;        // 64-aligned, no batch straddle
    const int bb = Mrow0 >> 11;

    if (z < 2) {
        u16* outp = (z == 0) ? v2 : k2;
        const float scale = (z == 0) ? 0.18033688011112042f : 1.0f;  // 0.125*log2(e)
        #pragma unroll
        for (int mi = 0; mi < 4; mi++)
            #pragma unroll
            for (int ni = 0; ni < 4; ni++) {
                const float bc = bias[colbase + wn * 64 + ni * 16 + l15];
                #pragma unroll
                for (int rg = 0; rg < 4; rg++)
                    ep[(mi * 16 + q4 + rg) * 80 + ni * 16 + l15] =
                        f2bf((acc[mi][ni][rg] + bc) * scale);
            }
        asm volatile("s_waitcnt lgkmcnt(0)" ::: "memory");
        const int s = (Mrow0 + lane) & (S_ - 1);
        u16* gb = outp + ((size_t)(bb * H_ + h) * S_ + s) * DK_;
        #pragma unroll
        for (int j = 0; j < 8; j++)
            *(uint4*)(gb + j * 8) = *(const uint4*)&ep[lane * 80 + j * 8];
    } else {
        #pragma unroll
        for (int mi = 0; mi < 4; mi++)
            #pragma unroll
            for (int ni = 0; ni < 4; ni++) {
                const float bc = bias[colbase + wn * 64 + ni * 16 + l15];
                uint2 pk;
                pk.x = pk2(acc[mi][ni][0] + bc, acc[mi][ni][1] + bc);
                pk.y = pk2(acc[mi][ni][2] + bc, acc[mi][ni][3] + bc);
                *(uint2*)&ep[(ni * 16 + l15) * 80 + mi * 16 + q4] = pk;
            }
        asm volatile("s_waitcnt lgkmcnt(0)" ::: "memory");
        const int s0g = Mrow0 & (S_ - 1);
        u16* gb = q2T + ((size_t)(bb * H_ + h) * DK_ + lane) * VST + s0g;
        #pragma unroll
        for (int j = 0; j < 8; j++)
            *(uint4*)(gb + j * 8) = *(const uint4*)&ep[lane * 80 + j * 8];
    }
}

// ---------------- flash attention (verbatim from R6) ----------------
// Roles (source bug): "query"=v2 (prescaled, log2 domain), "key"=k2, "value"=q2.
// bh = id&31 -> the 16 s-blocks of one (b,h) share an XCD's L2.

__global__ __launch_bounds__(256) void flash_attn(
    const u16* __restrict__ v2, const u16* __restrict__ k2,
    const u16* __restrict__ q2T, u16* __restrict__ Ob)
{
    __shared__ alignas(16) u16 lK[2][64 * 64];
    __shared__ alignas(16) u16 lV[2][64 * 64];
    __shared__ alignas(16) u16 ldsP[4][2][16][68];  // [wave][group][s][t+pad]

    const int tid = threadIdx.x;
    const int lane = tid & 63, wave = tid >> 6;
    const int q = lane >> 4, l15 = lane & 15;
    const int q4 = q * 4;
    const int bh = blockIdx.x & 31;
    const int sbase = (blockIdx.x >> 5) * 128;

    const u16* Qp = v2  + (size_t)bh * S_ * DK_;
    const u16* Kp = k2  + (size_t)bh * S_ * DK_;
    const u16* Vp = q2T + (size_t)bh * DK_ * VST;

    const int srow8 = lane >> 3;
    const int cs    = lane & 7;
    const int cg    = cs ^ srow8;
    const int krow0 = wave * 16 + srow8;

    bf16x8 bq[2][2];
    #pragma unroll
    for (int g = 0; g < 2; g++) {
        const u16* qp = Qp + (size_t)(sbase + g * 64 + wave * 16 + l15) * DK_ + q * 8;
        bq[g][0] = *(const bf16x8*)(qp);
        bq[g][1] = *(const bf16x8*)(qp + 32);
    }

    bf16x8 ones;
    #pragma unroll
    for (int i = 0; i < 8; i++) ones[i] = (short)0x3F80;

    f32x4 o_acc[2][4] = {};
    f32x4 o_l[2] = {};

    const int sw = l15 & 7;
    const int fc0 = (q ^ sw) * 8;
    const int fc1 = fc0 ^ 32;

    {
        const u16* kg = Kp + (size_t)krow0 * DK_ + cg * 8;
        const u16* vg = Vp + (size_t)krow0 * VST + cg * 8;
        u16* lkd = &lK[0][(wave * 128) * 8 + lane * 8];
        u16* lvd = &lV[0][(wave * 128) * 8 + lane * 8];
        gld16(kg, lkd);
        gld16(kg + 8 * DK_, lkd + 64 * 8);
        gld16(vg, lvd);
        gld16(vg + (size_t)8 * VST, lvd + 64 * 8);
    }

    for (int it = 0; it < S_ / 64; ++it) {
        const int buf = it & 1;
        __syncthreads();
        if (it + 1 < S_ / 64) {
            const int nb = (it + 1) & 1;
            const int t1 = (it + 1) * 64;
            const u16* kg = Kp + (size_t)(t1 + krow0) * DK_ + cg * 8;
            const u16* vg = Vp + (size_t)krow0 * VST + t1 + cg * 8;
            u16* lkd = &lK[nb][(wave * 128) * 8 + lane * 8];
            u16* lvd = &lV[nb][(wave * 128) * 8 + lane * 8];
            gld16(kg, lkd);
            gld16(kg + 8 * DK_, lkd + 64 * 8);
            gld16(vg, lvd);
            gld16(vg + (size_t)8 * VST, lvd + 64 * 8);
        }

        f32x4 s_acc[2][4];
        #pragma unroll
        for (int mi = 0; mi < 4; mi++) {
            const int trow = mi * 16 + l15;
            bf16x8 a0 = *(const bf16x8*)&lK[buf][trow * 64 + fc0];
            bf16x8 a1 = *(const bf16x8*)&lK[buf][trow * 64 + fc1];
            #pragma unroll
            for (int g = 0; g < 2; g++) {
                f32x4 zz = {};
                zz = MFMA(a0, bq[g][0], zz);
                s_acc[g][mi] = MFMA(a1, bq[g][1], zz);
            }
        }

        #pragma unroll
        for (int g = 0; g < 2; g++)
            #pragma unroll
            for (int mi = 0; mi < 4; mi++) {
                float p0 = EXP2(s_acc[g][mi][0]);
                float p1 = EXP2(s_acc[g][mi][1]);
                float p2 = EXP2(s_acc[g][mi][2]);
                float p3 = EXP2(s_acc[g][mi][3]);
                uint2 pk;
                pk.x = __builtin_amdgcn_perm(__float_as_uint(p1), __float_as_uint(p0), 0x07060302u);
                pk.y = __builtin_amdgcn_perm(__float_as_uint(p3), __float_as_uint(p2), 0x07060302u);
                *(uint2*)&ldsP[wave][g][l15][mi * 16 + q4] = pk;
            }

        asm volatile("s_waitcnt lgkmcnt(0)" ::: "memory");

        bf16x8 bp[2][2];
        #pragma unroll
        for (int g = 0; g < 2; g++) {
            uint2* r0 = (uint2*)&bp[g][0];
            r0[0] = *(const uint2*)&ldsP[wave][g][l15][q * 8];
            r0[1] = *(const uint2*)&ldsP[wave][g][l15][q * 8 + 4];
            uint2* r1 = (uint2*)&bp[g][1];
            r1[0] = *(const uint2*)&ldsP[wave][g][l15][32 + q * 8];
            r1[1] = *(const uint2*)&ldsP[wave][g][l15][32 + q * 8 + 4];
        }

        #pragma unroll
        for (int mi = 0; mi < 4; mi++) {
            const int dkrow = mi * 16 + l15;
            bf16x8 av0 = *(const bf16x8*)&lV[buf][dkrow * 64 + fc0];
            bf16x8 av1 = *(const bf16x8*)&lV[buf][dkrow * 64 + fc1];
            #pragma unroll
            for (int g = 0; g < 2; g++) {
                o_acc[g][mi] = MFMA(av0, bp[g][0], o_acc[g][mi]);
                o_acc[g][mi] = MFMA(av1, bp[g][1], o_acc[g][mi]);
            }
        }
        #pragma unroll
        for (int g = 0; g < 2; g++) {
            o_l[g] = MFMA(ones, bp[g][0], o_l[g]);
            o_l[g] = MFMA(ones, bp[g][1], o_l[g]);
        }

        asm volatile("s_barrier" ::: "memory");
    }

    const int bb = bh >> 4, h = bh & 15;
    #pragma unroll
    for (int g = 0; g < 2; g++) {
        const float inv_l = 1.0f / o_l[g][0];
        const int s = sbase + g * 64 + wave * 16 + l15;
        #pragma unroll
        for (int mi = 0; mi < 4; mi++) {
            ushort4 o4;
            o4.x = f2bf(o_acc[g][mi][0] * inv_l);
            o4.y = f2bf(o_acc[g][mi][1] * inv_l);
            o4.z = f2bf(o_acc[g][mi][2] * inv_l);
            o4.w = f2bf(o_acc[g][mi][3] * inv_l);
            *(ushort4*)(Ob + (size_t)(bb * S_ + s) * (H_ * DK_) + h * DK_ + mi * 16 + q4) = o4;
        }
    }
}

// ---------------- output GEMM: out = O @ Wo^T + bo (bf16 in, BK=64) ----------

__global__ __launch_bounds__(256) void out_gemm(
    const u16* __restrict__ Ob, const u16* __restrict__ Wob,
    const float* __restrict__ bo, float* __restrict__ out)
{
    __shared__ alignas(16) u16 lA[128 * 64];   // 16 KB
    __shared__ alignas(16) u16 lB[64 * 64];    // 8 KB

    const int tid = threadIdx.x;
    const int lane = tid & 63, wave = tid >> 6;
    const int wm = wave >> 1, wn = wave & 1;   // 2x2 waves: 64M x 32N each
    const int q = lane >> 4, l15 = lane & 15;
    const int q4 = q * 4;

    // XCD grouping: f = y*16+x; M-block = f&31
    const int f = blockIdx.y * 16 + blockIdx.x;
    const int rowbase = (f & 31) * 128;
    const int colbase = (f >> 5) * 64;

    const int srow = wave * 8 + (lane >> 3);
    const int cg = (lane & 7) ^ (lane >> 3);
    const u16* gA = Ob  + (size_t)(rowbase + srow) * D_ + cg * 8;
    const u16* gW = Wob + (size_t)(colbase + srow) * D_ + cg * 8;
    u16* lAp = lA + wave * 512 + lane * 8;
    u16* lBp = lB + wave * 512 + lane * 8;

    const int sw = l15 & 7;
    const int fo0 = (q ^ sw) * 8;
    const int fo1 = fo0 ^ 32;

    f32x4 acc[4][2] = {};

    for (int k0 = 0; k0 < D_; k0 += 64) {
        #pragma unroll
        for (int j = 0; j < 4; j++)
            gld16(gA + k0 + (size_t)j * 32 * D_, lAp + j * 2048);
        #pragma unroll
        for (int j = 0; j < 2; j++)
            gld16(gW + k0 + (size_t)j * 32 * D_, lBp + j * 2048);
        __syncthreads();
        bf16x8 a0[4], a1[4], b0[2], b1[2];
        #pragma unroll
        for (int mi = 0; mi < 4; mi++) {
            const int r = (wm * 64 + mi * 16 + l15) * 64;
            a0[mi] = *(const bf16x8*)&lA[r + fo0];
            a1[mi] = *(const bf16x8*)&lA[r + fo1];
        }
        #pragma unroll
        for (int ni = 0; ni < 2; ni++) {
            const int r = (wn * 32 + ni * 16 + l15) * 64;
            b0[ni] = *(const bf16x8*)&lB[r + fo0];
            b1[ni] = *(const bf16x8*)&lB[r + fo1];
        }
        #pragma unroll
        for (int mi = 0; mi < 4; mi++)
            #pragma unroll
            for (int ni = 0; ni < 2; ni++) {
                acc[mi][ni] = MFMA(a0[mi], b0[ni], acc[mi][ni]);
                acc[mi][ni] = MFMA(a1[mi], b1[ni], acc[mi][ni]);
            }
        __syncthreads();
    }

    #pragma unroll
    for (int mi = 0; mi < 4; mi++)
        #pragma unroll
        for (int ni = 0; ni < 2; ni++) {
            const int c = colbase + wn * 32 + ni * 16 + l15;
            const float bc = bo[c];
            #pragma unroll
            for (int rg = 0; rg < 4; rg++) {
                const int r = rowbase + wm * 64 + mi * 16 + q4 + rg;
                out[(size_t)r * D_ + c] = acc[mi][ni][rg] + bc;
            }
        }
}

// ---------------- launch ----------------

extern "C" void kernel_launch(void* const* d_in, const int* in_sizes, int n_in,
                              void* d_out, int out_size, void* d_ws, size_t ws_size,
                              hipStream_t stream) {
    const float* v  = (const float*)d_in[0];
    const float* k  = (const float*)d_in[1];
    const float* qq = (const float*)d_in[2];
    const float* Wq = (const float*)d_in[3];
    const float* bq = (const float*)d_in[4];
    const float* Wk = (const float*)d_in[5];
    const float* bk = (const float*)d_in[6];
    const float* Wv = (const float*)d_in[7];
    const float* bv = (const float*)d_in[8];
    const float* Wo = (const float*)d_in[9];
    const float* bo = (const float*)d_in[10];
    float* out = (float*)d_out;

    char* w = (char*)d_ws;
    u16* cvtb = (u16*)w;                // 32 MB bf16 arena: vb|kb|qb|Wvb|Wkb|Wqb|Wob
    u16* v2  = (u16*)(w + 33554432);    // 8 MiB (B,H,S,DK), prescaled 0.125*log2e
    u16* k2  = (u16*)(w + 41943040);    // 8 MiB (B,H,S,DK)
    u16* q2T = (u16*)(w + 50331648);    // (B,H,DK,VST) bf16 padded: 8,912,896 B
    u16* Ob  = (u16*)(w + 59244544);    // 8 MiB (B,S,H*DK) bf16

    conv_all<<<16384, 256, 0, stream>>>(v, k, qq, Wv, Wk, Wq, Wo, cvtb);
    // proj: z=0 uses (v, Wv)->v2, z=1 (k, Wk)->k2, z=2 (q, Wq)->q2T
    proj_gemm<<<dim3(8, 32, 3), 256, 0, stream>>>(cvtb, cvtb + 12582912,
                                                  bv, bk, bq, v2, k2, q2T);
    flash_attn<<<512, 256, 0, stream>>>(v2, k2, q2T, Ob);
    out_gemm<<<dim3(16, 32), 256, 0, stream>>>(Ob, cvtb + 15728640, bo, out);
}

// Round 8
// 216.730 us; speedup vs baseline: 1.2839x; 1.0449x over previous
//
#include <hip/hip_runtime.h>
#include <stdint.h>

#define B_  2
#define S_  2048
#define D_  1024
#define H_  16
#define DK_ 64
#define VST 2176   // q2T padded row stride (4352 B = 17*256): breaks 4KB aliasing

typedef unsigned short u16;
typedef short bf16x8 __attribute__((ext_vector_type(8)));
typedef float f32x4  __attribute__((ext_vector_type(4)));

#define MFMA(a,b,c) __builtin_amdgcn_mfma_f32_16x16x32_bf16((a),(b),(c),0,0,0)
#define EXP2(x) __builtin_amdgcn_exp2f(x)

static __device__ __forceinline__ u16 f2bf(float f) {
    uint32_t u = __float_as_uint(f);
    u += 0x7fffu + ((u >> 16) & 1u);   // RNE
    return (u16)(u >> 16);
}
static __device__ __forceinline__ uint32_t pk2(float x, float y) {
    return __builtin_amdgcn_perm(__float_as_uint(y) + 0x8000u,
                                 __float_as_uint(x) + 0x8000u, 0x07060302u);
}

typedef const __attribute__((address_space(1))) void* gas_p;
typedef __attribute__((address_space(3))) void* las_p;
static __device__ __forceinline__ void gld16(const void* g, void* l) {
    __builtin_amdgcn_global_load_lds((gas_p)g, (las_p)l, 16, 0, 0);
}

// ---------------- one fused f32 -> bf16 conversion pass ----------------
// bf16 arena layout (u16 element offsets):
//   vb 0 | kb 4194304 | qb 8388608 | Wvb 12582912 | Wkb 13631488
//   Wqb 14680064 | Wob 15728640     (total 16M u16 = 32 MB)

__global__ void conv_all(const float* __restrict__ v, const float* __restrict__ k,
                         const float* __restrict__ q,
                         const float* __restrict__ Wv, const float* __restrict__ Wk,
                         const float* __restrict__ Wq, const float* __restrict__ Wo,
                         u16* __restrict__ dst) {
    const int b = blockIdx.x;
    const float* s;
    size_t loc, segbase;
    if (b < 12288) {                          // 3 X tensors, 4096 blocks each
        const int t = b >> 12;
        s = (t == 0) ? v : (t == 1 ? k : q);
        segbase = (size_t)t * 4194304;
        loc = (size_t)(b & 4095) * 1024;
    } else {                                  // 4 W tensors, 1024 blocks each
        const int t = (b - 12288) >> 10;
        s = (t == 0) ? Wv : (t == 1 ? Wk : (t == 2 ? Wq : Wo));
        segbase = 12582912 + (size_t)t * 1048576;
        loc = (size_t)(b & 1023) * 1024;
    }
    loc += threadIdx.x * 4;
    float4 f = *(const float4*)(s + loc);
    ushort4 o;
    o.x = f2bf(f.x); o.y = f2bf(f.y); o.z = f2bf(f.z); o.w = f2bf(f.w);
    *(ushort4*)(dst + segbase + loc) = o;
}

// ---------------- projection GEMMs: C = X @ W^T + bias (bf16, BK=64) ----------
// (verbatim from R7 — proven)

__global__ __launch_bounds__(256) void proj_gemm(
    const u16* __restrict__ Xb, const u16* __restrict__ Wb,
    const float* __restrict__ bv, const float* __restrict__ bk, const float* __restrict__ bq,
    u16* __restrict__ v2, u16* __restrict__ k2, u16* __restrict__ q2T)
{
    __shared__ alignas(16) char smem[40960];   // union: lA(16K)+lB(16K) / epi(40K)
    u16* lA = (u16*)smem;                      // 128 x 64 bf16
    u16* lB = (u16*)(smem + 16384);
    u16* epi = (u16*)smem;                     // [wave][64][80] u16

    const int z = blockIdx.z;
    const u16* A = Xb + (size_t)z * 4194304;   // v / k / q (bf16)
    const u16* W = Wb + (size_t)z * 1048576;   // Wv / Wk / Wq (bf16)
    const float* bias = (z == 0) ? bv : (z == 1 ? bk : bq);

    const int tid = threadIdx.x;
    const int lane = tid & 63, wave = tid >> 6;
    const int wm = wave >> 1, wn = wave & 1;
    const int q = lane >> 4, l15 = lane & 15;
    const int q4 = q * 4;

    const int f = blockIdx.y * 8 + blockIdx.x;
    const int rowbase = (f & 31) * 128;
    const int colbase = (f >> 5) * 128;

    const int srow = wave * 8 + (lane >> 3);
    const int cg = (lane & 7) ^ (lane >> 3);
    const u16* gA = A + (size_t)(rowbase + srow) * D_ + cg * 8;
    const u16* gW = W + (size_t)(colbase + srow) * D_ + cg * 8;
    u16* lAp = lA + wave * 512 + lane * 8;
    u16* lBp = lB + wave * 512 + lane * 8;

    const int sw = l15 & 7;
    const int fo0 = (q ^ sw) * 8;
    const int fo1 = fo0 ^ 32;

    f32x4 acc[4][4] = {};

    for (int k0 = 0; k0 < D_; k0 += 64) {
        #pragma unroll
        for (int j = 0; j < 4; j++) {
            gld16(gA + k0 + (size_t)j * 32 * D_, lAp + j * 2048);
            gld16(gW + k0 + (size_t)j * 32 * D_, lBp + j * 2048);
        }
        __syncthreads();
        bf16x8 a0[4], a1[4], b0[4], b1[4];
        #pragma unroll
        for (int mi = 0; mi < 4; mi++) {
            const int r = (wm * 64 + mi * 16 + l15) * 64;
            a0[mi] = *(const bf16x8*)&lA[r + fo0];
            a1[mi] = *(const bf16x8*)&lA[r + fo1];
        }
        #pragma unroll
        for (int ni = 0; ni < 4; ni++) {
            const int r = (wn * 64 + ni * 16 + l15) * 64;
            b0[ni] = *(const bf16x8*)&lB[r + fo0];
            b1[ni] = *(const bf16x8*)&lB[r + fo1];
        }
        #pragma unroll
        for (int mi = 0; mi < 4; mi++)
            #pragma unroll
            for (int ni = 0; ni < 4; ni++) {
                acc[mi][ni] = MFMA(a0[mi], b0[ni], acc[mi][ni]);
                acc[mi][ni] = MFMA(a1[mi], b1[ni], acc[mi][ni]);
            }
        __syncthreads();
    }

    u16* ep = epi + wave * (64 * 80);
    const int h = (colbase + wn * 64) >> 6;
    const int Mrow0 = rowbase + wm * 64;
    const int bb = Mrow0 >> 11;

    if (z < 2) {
        u16* outp = (z == 0) ? v2 : k2;
        const float scale = (z == 0) ? 0.18033688011112042f : 1.0f;  // 0.125*log2(e)
        #pragma unroll
        for (int mi = 0; mi < 4; mi++)
            #pragma unroll
            for (int ni = 0; ni < 4; ni++) {
                const float bc = bias[colbase + wn * 64 + ni * 16 + l15];
                #pragma unroll
                for (int rg = 0; rg < 4; rg++)
                    ep[(mi * 16 + q4 + rg) * 80 + ni * 16 + l15] =
                        f2bf((acc[mi][ni][rg] + bc) * scale);
            }
        asm volatile("s_waitcnt lgkmcnt(0)" ::: "memory");
        const int s = (Mrow0 + lane) & (S_ - 1);
        u16* gb = outp + ((size_t)(bb * H_ + h) * S_ + s) * DK_;
        #pragma unroll
        for (int j = 0; j < 8; j++)
            *(uint4*)(gb + j * 8) = *(const uint4*)&ep[lane * 80 + j * 8];
    } else {
        #pragma unroll
        for (int mi = 0; mi < 4; mi++)
            #pragma unroll
            for (int ni = 0; ni < 4; ni++) {
                const float bc = bias[colbase + wn * 64 + ni * 16 + l15];
                uint2 pk;
                pk.x = pk2(acc[mi][ni][0] + bc, acc[mi][ni][1] + bc);
                pk.y = pk2(acc[mi][ni][2] + bc, acc[mi][ni][3] + bc);
                *(uint2*)&ep[(ni * 16 + l15) * 80 + mi * 16 + q4] = pk;
            }
        asm volatile("s_waitcnt lgkmcnt(0)" ::: "memory");
        const int s0g = Mrow0 & (S_ - 1);
        u16* gb = q2T + ((size_t)(bb * H_ + h) * DK_ + lane) * VST + s0g;
        #pragma unroll
        for (int j = 0; j < 8; j++)
            *(uint4*)(gb + j * 8) = *(const uint4*)&ep[lane * 80 + j * 8];
    }
}

// ---------------- flash attention v4: g=4 + intra-block t-split ----------------
// Roles (source bug): "query"=v2 (prescaled, log2 domain), "key"=k2, "value"=q2.
// 512 threads = 8 waves. Waves 0-3: t in [0,1024); waves 4-7: t in [1024,2048).
// Each wave: 64 s-rows (4 groups of 16) -> each K/V b128 fragment feeds 4 MFMAs
// (1.5x less LDS traffic per MFMA than g=2). Halves hold private dbuf K/V tiles.
// Partial (o,l) are additive (no online max) -> combined in-LDS at epilogue.

__global__ __launch_bounds__(512, 2) void flash_attn(
    const u16* __restrict__ v2, const u16* __restrict__ k2,
    const u16* __restrict__ q2T, u16* __restrict__ Ob)
{
    __shared__ alignas(16) char smem[82944];
    // loop phase:
    u16* lK   = (u16*)smem;                  // [th 2][buf 2][64*64]
    u16* lV   = (u16*)(smem + 32768);        // [th 2][buf 2][64*64]
    u16* ldsP = (u16*)(smem + 65536);        // [wave 8][16][68]
    // epilogue phase (overlays loop buffers, barrier-separated):
    float* Xo = (float*)smem;                // [wl 4][64 s][68] f32
    float* Xl = (float*)(smem + 69632);      // [256] f32

    const int tid = threadIdx.x;
    const int lane = tid & 63, wave = tid >> 6;
    const int th = wave >> 2, wl = wave & 3;   // t-half, wave-in-half
    const int q = lane >> 4, l15 = lane & 15;
    const int q4 = q * 4;
    const int bh = blockIdx.x & 31;            // XCD grouping
    const int sbase = (blockIdx.x >> 5) * 256;
    const int tbase = th * 1024;

    const u16* Qp = v2  + (size_t)bh * S_ * DK_;
    const u16* Kp = k2  + (size_t)bh * S_ * DK_;
    const u16* Vp = q2T + (size_t)bh * DK_ * VST;

    // staging lane geometry (proven 0-conflict)
    const int srow8 = lane >> 3;
    const int cs    = lane & 7;
    const int cg    = cs ^ srow8;
    const int krow0 = wl * 16 + srow8;         // row within 64-row tile
    u16* lKh = lK + th * 8192;                 // our half's dbuf base
    u16* lVh = lV + th * 8192;

    // B operands (Q^T) for 4 s-groups
    bf16x8 bq[4][2];
    #pragma unroll
    for (int g = 0; g < 4; g++) {
        const u16* qp = Qp + (size_t)(sbase + wl * 64 + g * 16 + l15) * DK_ + q * 8;
        bq[g][0] = *(const bf16x8*)(qp);
        bq[g][1] = *(const bf16x8*)(qp + 32);
    }

    bf16x8 ones;
    #pragma unroll
    for (int i = 0; i < 8; i++) ones[i] = (short)0x3F80;

    f32x4 o_acc[4][4] = {};   // [g][mi]: O^T[dk=mi*16+q4+rg][s-group g]
    f32x4 o_l[4] = {};

    const int sw = l15 & 7;
    const int fc0 = (q ^ sw) * 8;
    const int fc1 = fc0 ^ 32;

    // prologue: stage tile it=0 of our half into buf 0
    {
        const u16* kg = Kp + (size_t)(tbase + krow0) * DK_ + cg * 8;
        const u16* vg = Vp + (size_t)krow0 * VST + tbase + cg * 8;
        u16* lkd = lKh + wl * 1024 + lane * 8;
        u16* lvd = lVh + wl * 1024 + lane * 8;
        gld16(kg, lkd);
        gld16(kg + 8 * DK_, lkd + 512);
        gld16(vg, lvd);
        gld16(vg + (size_t)8 * VST, lvd + 512);
    }

    u16* Pw = ldsP + wave * (16 * 68);

    for (int it = 0; it < 16; ++it) {
        const int buf = it & 1;
        __syncthreads();   // stage(it) drained; all waves done with buf from it-2
        if (it + 1 < 16) {
            const int t1 = tbase + (it + 1) * 64;
            const u16* kg = Kp + (size_t)(t1 + krow0) * DK_ + cg * 8;
            const u16* vg = Vp + (size_t)krow0 * VST + t1 + cg * 8;
            u16* lkd = lKh + (buf ^ 1) * 4096 + wl * 1024 + lane * 8;
            u16* lvd = lVh + (buf ^ 1) * 4096 + wl * 1024 + lane * 8;
            gld16(kg, lkd);
            gld16(kg + 8 * DK_, lkd + 512);
            gld16(vg, lvd);
            gld16(vg + (size_t)8 * VST, lvd + 512);
        }

        // all K/V fragments up front (deep LDS queue, reused across 4 s-groups)
        const u16* Kt = lKh + buf * 4096;
        const u16* Vt = lVh + buf * 4096;
        bf16x8 ak0[4], ak1[4], av0[4], av1[4];
        #pragma unroll
        for (int mi = 0; mi < 4; mi++) {
            const int r = (mi * 16 + l15) * 64;
            ak0[mi] = *(const bf16x8*)&Kt[r + fc0];
            ak1[mi] = *(const bf16x8*)&Kt[r + fc1];
            av0[mi] = *(const bf16x8*)&Vt[r + fc0];
            av1[mi] = *(const bf16x8*)&Vt[r + fc1];
        }

        #pragma unroll
        for (int g = 0; g < 4; g++) {
            // S^T tile for this s-group: 64(t) x 16(s)
            f32x4 sa[4];
            #pragma unroll
            for (int mi = 0; mi < 4; mi++) {
                f32x4 zz = {};
                zz = MFMA(ak0[mi], bq[g][0], zz);
                sa[mi] = MFMA(ak1[mi], bq[g][1], zz);
            }
            // P = exp2(s), trunc-pack, stash (proven pad-68 pattern)
            #pragma unroll
            for (int mi = 0; mi < 4; mi++) {
                float p0 = EXP2(sa[mi][0]);
                float p1 = EXP2(sa[mi][1]);
                float p2 = EXP2(sa[mi][2]);
                float p3 = EXP2(sa[mi][3]);
                uint2 pk;
                pk.x = __builtin_amdgcn_perm(__float_as_uint(p1), __float_as_uint(p0), 0x07060302u);
                pk.y = __builtin_amdgcn_perm(__float_as_uint(p3), __float_as_uint(p2), 0x07060302u);
                *(uint2*)&Pw[l15 * 68 + mi * 16 + q4] = pk;
            }
            asm volatile("s_waitcnt lgkmcnt(0)" ::: "memory");
            bf16x8 bp0, bp1;
            {
                uint2* r0 = (uint2*)&bp0;
                r0[0] = *(const uint2*)&Pw[l15 * 68 + q * 8];
                r0[1] = *(const uint2*)&Pw[l15 * 68 + q * 8 + 4];
                uint2* r1 = (uint2*)&bp1;
                r1[0] = *(const uint2*)&Pw[l15 * 68 + 32 + q * 8];
                r1[1] = *(const uint2*)&Pw[l15 * 68 + 32 + q * 8 + 4];
            }
            #pragma unroll
            for (int mi = 0; mi < 4; mi++) {
                o_acc[g][mi] = MFMA(av0[mi], bp0, o_acc[g][mi]);
                o_acc[g][mi] = MFMA(av1[mi], bp1, o_acc[g][mi]);
            }
            o_l[g] = MFMA(ones, bp0, o_l[g]);
            o_l[g] = MFMA(ones, bp1, o_l[g]);
        }
    }

    // ---- combine the two t-halves in LDS, then store Ob ----
    __syncthreads();
    if (th == 1) {
        #pragma unroll
        for (int g = 0; g < 4; g++) {
            const int sr = wl * 64 + g * 16 + l15;
            #pragma unroll
            for (int mi = 0; mi < 4; mi++)
                *(f32x4*)&Xo[sr * 68 + mi * 16 + q4] = o_acc[g][mi];
            if (q == 0) Xl[sr] = o_l[g][0];
        }
    }
    __syncthreads();
    if (th == 0) {
        const int bb = bh >> 4, h = bh & 15;
        #pragma unroll
        for (int g = 0; g < 4; g++) {
            const int sr = wl * 64 + g * 16 + l15;
            const float inv_l = 1.0f / (o_l[g][0] + Xl[sr]);
            const int s = sbase + sr;
            #pragma unroll
            for (int mi = 0; mi < 4; mi++) {
                f32x4 p = *(const f32x4*)&Xo[sr * 68 + mi * 16 + q4];
                ushort4 o4;
                o4.x = f2bf((o_acc[g][mi][0] + p[0]) * inv_l);
                o4.y = f2bf((o_acc[g][mi][1] + p[1]) * inv_l);
                o4.z = f2bf((o_acc[g][mi][2] + p[2]) * inv_l);
                o4.w = f2bf((o_acc[g][mi][3] + p[3]) * inv_l);
                *(ushort4*)(Ob + (size_t)(bb * S_ + s) * (H_ * DK_) + h * DK_ + mi * 16 + q4) = o4;
            }
        }
    }
}

// ---------------- output GEMM: out = O @ Wo^T + bo (bf16 in, BK=64) ----------
// (verbatim from R7)

__global__ __launch_bounds__(256) void out_gemm(
    const u16* __restrict__ Ob, const u16* __restrict__ Wob,
    const float* __restrict__ bo, float* __restrict__ out)
{
    __shared__ alignas(16) u16 lA[128 * 64];   // 16 KB
    __shared__ alignas(16) u16 lB[64 * 64];    // 8 KB

    const int tid = threadIdx.x;
    const int lane = tid & 63, wave = tid >> 6;
    const int wm = wave >> 1, wn = wave & 1;
    const int q = lane >> 4, l15 = lane & 15;
    const int q4 = q * 4;

    const int f = blockIdx.y * 16 + blockIdx.x;
    const int rowbase = (f & 31) * 128;
    const int colbase = (f >> 5) * 64;

    const int srow = wave * 8 + (lane >> 3);
    const int cg = (lane & 7) ^ (lane >> 3);
    const u16* gA = Ob  + (size_t)(rowbase + srow) * D_ + cg * 8;
    const u16* gW = Wob + (size_t)(colbase + srow) * D_ + cg * 8;
    u16* lAp = lA + wave * 512 + lane * 8;
    u16* lBp = lB + wave * 512 + lane * 8;

    const int sw = l15 & 7;
    const int fo0 = (q ^ sw) * 8;
    const int fo1 = fo0 ^ 32;

    f32x4 acc[4][2] = {};

    for (int k0 = 0; k0 < D_; k0 += 64) {
        #pragma unroll
        for (int j = 0; j < 4; j++)
            gld16(gA + k0 + (size_t)j * 32 * D_, lAp + j * 2048);
        #pragma unroll
        for (int j = 0; j < 2; j++)
            gld16(gW + k0 + (size_t)j * 32 * D_, lBp + j * 2048);
        __syncthreads();
        bf16x8 a0[4], a1[4], b0[2], b1[2];
        #pragma unroll
        for (int mi = 0; mi < 4; mi++) {
            const int r = (wm * 64 + mi * 16 + l15) * 64;
            a0[mi] = *(const bf16x8*)&lA[r + fo0];
            a1[mi] = *(const bf16x8*)&lA[r + fo1];
        }
        #pragma unroll
        for (int ni = 0; ni < 2; ni++) {
            const int r = (wn * 32 + ni * 16 + l15) * 64;
            b0[ni] = *(const bf16x8*)&lB[r + fo0];
            b1[ni] = *(const bf16x8*)&lB[r + fo1];
        }
        #pragma unroll
        for (int mi = 0; mi < 4; mi++)
            #pragma unroll
            for (int ni = 0; ni < 2; ni++) {
                acc[mi][ni] = MFMA(a0[mi], b0[ni], acc[mi][ni]);
                acc[mi][ni] = MFMA(a1[mi], b1[ni], acc[mi][ni]);
            }
        __syncthreads();
    }

    #pragma unroll
    for (int mi = 0; mi < 4; mi++)
        #pragma unroll
        for (int ni = 0; ni < 2; ni++) {
            const int c = colbase + wn * 32 + ni * 16 + l15;
            const float bc = bo[c];
            #pragma unroll
            for (int rg = 0; rg < 4; rg++) {
                const int r = rowbase + wm * 64 + mi * 16 + q4 + rg;
                out[(size_t)r * D_ + c] = acc[mi][ni][rg] + bc;
            }
        }
}

// ---------------- launch ----------------

extern "C" void kernel_launch(void* const* d_in, const int* in_sizes, int n_in,
                              void* d_out, int out_size, void* d_ws, size_t ws_size,
                              hipStream_t stream) {
    const float* v  = (const float*)d_in[0];
    const float* k  = (const float*)d_in[1];
    const float* qq = (const float*)d_in[2];
    const float* Wq = (const float*)d_in[3];
    const float* bq = (const float*)d_in[4];
    const float* Wk = (const float*)d_in[5];
    const float* bk = (const float*)d_in[6];
    const float* Wv = (const float*)d_in[7];
    const float* bv = (const float*)d_in[8];
    const float* Wo = (const float*)d_in[9];
    const float* bo = (const float*)d_in[10];
    float* out = (float*)d_out;

    char* w = (char*)d_ws;
    u16* cvtb = (u16*)w;                // 32 MB bf16 arena: vb|kb|qb|Wvb|Wkb|Wqb|Wob
    u16* v2  = (u16*)(w + 33554432);    // 8 MiB (B,H,S,DK), prescaled 0.125*log2e
    u16* k2  = (u16*)(w + 41943040);    // 8 MiB (B,H,S,DK)
    u16* q2T = (u16*)(w + 50331648);    // (B,H,DK,VST) bf16 padded: 8,912,896 B
    u16* Ob  = (u16*)(w + 59244544);    // 8 MiB (B,S,H*DK) bf16

    conv_all<<<16384, 256, 0, stream>>>(v, k, qq, Wv, Wk, Wq, Wo, cvtb);
    proj_gemm<<<dim3(8, 32, 3), 256, 0, stream>>>(cvtb, cvtb + 12582912,
                                                  bv, bk, bq, v2, k2, q2T);
    flash_attn<<<256, 512, 0, stream>>>(v2, k2, q2T, Ob);
    out_gemm<<<dim3(16, 32), 256, 0, stream>>>(Ob, cvtb + 15728640, bo, out);
}